// Round 2
// baseline (1231.269 us; speedup 1.0000x reference)
//
#include <hip/hip_runtime.h>

typedef unsigned short u16;
typedef __attribute__((ext_vector_type(8))) short bf16x8;
typedef __attribute__((ext_vector_type(4))) float f32x4;

__device__ __forceinline__ u16 f2bf(float x) {
  unsigned int u = __float_as_uint(x);
  u = u + 0x7FFFu + ((u >> 16) & 1u);
  return (u16)(u >> 16);
}
__device__ __forceinline__ float bf2f(u16 v) {
  return __uint_as_float(((unsigned int)v) << 16);
}

typedef const __attribute__((address_space(1))) void gas_void;
typedef __attribute__((address_space(3))) void las_void;

__device__ __forceinline__ void gld_lds16(const u16* g, u16* l) {
  __builtin_amdgcn_global_load_lds((gas_void*)g, (las_void*)l, 16, 0, 0);
}

#define BM 128
#define BN 128
#define BK 32

// stage a [128][32] bf16 tile from row-major src (leading dim lda) into linear LDS
__device__ __forceinline__ void stage_tile(const u16* __restrict__ src, long lda,
                                           long row0, long k0, u16* ldst, int tid) {
  int wave = tid >> 6;
#pragma unroll
  for (int c = 0; c < 2; ++c) {
    int chunk = c * 256 + tid;      // 512 chunks x 8 elems = 128*32
    int r = chunk >> 2;
    int col = (chunk & 3) * 8;
    const u16* g = src + (row0 + r) * lda + k0 + col;
    u16* l = ldst + c * 2048 + wave * 512;  // HW adds lane*16B
    gld_lds16(g, l);
  }
}

// C[m][n] = sum_k A[m][k]*B[n][k]  (both row-major, K contiguous)
// MODE 0: split3 (A0+A1, B0+B1), epilogue C = 2*acc - aux0[n]        (logits)
// MODE 1: plain, C = acc                                              (z_e)
// MODE 2: plain, C = acc + aux0[m*ldc+n] + aux1[n]                    (z_q)
template <int MODE>
__global__ __launch_bounds__(256) void gemm_bt(
    const u16* __restrict__ A0, const u16* __restrict__ A1, long lda,
    const u16* __restrict__ B0, const u16* __restrict__ B1, long ldb,
    float* __restrict__ C, long ldc, int K,
    const float* __restrict__ aux0, const float* __restrict__ aux1) {
  __shared__ __align__(16) u16 lA0[BM * BK];
  __shared__ __align__(16) u16 lB0[BN * BK];
  __shared__ __align__(16) u16 lA1[(MODE == 0) ? BM * BK : 8];
  __shared__ __align__(16) u16 lB1[(MODE == 0) ? BN * BK : 8];

  int tid = threadIdx.x;
  int wave = tid >> 6, lane = tid & 63;
  long bm = (long)blockIdx.y * BM, bn = (long)blockIdx.x * BN;
  int wm = (wave >> 1) * 64, wn = (wave & 1) * 64;
  int r15 = lane & 15, kg = lane >> 4;

  f32x4 acc[4][4];
#pragma unroll
  for (int i = 0; i < 4; ++i)
#pragma unroll
    for (int j = 0; j < 4; ++j) acc[i][j] = (f32x4){0.f, 0.f, 0.f, 0.f};

  for (int k0 = 0; k0 < K; k0 += BK) {
    __syncthreads();
    stage_tile(A0, lda, bm, k0, lA0, tid);
    stage_tile(B0, ldb, bn, k0, lB0, tid);
    if constexpr (MODE == 0) {
      stage_tile(A1, lda, bm, k0, lA1, tid);
      stage_tile(B1, ldb, bn, k0, lB1, tid);
    }
    __syncthreads();

    bf16x8 ah[4], bh[4];
#pragma unroll
    for (int i = 0; i < 4; ++i) {
      ah[i] = *(const bf16x8*)&lA0[(wm + i * 16 + r15) * BK + kg * 8];
      bh[i] = *(const bf16x8*)&lB0[(wn + i * 16 + r15) * BK + kg * 8];
    }
    if constexpr (MODE == 0) {
      bf16x8 al[4], bl[4];
#pragma unroll
      for (int i = 0; i < 4; ++i) {
        al[i] = *(const bf16x8*)&lA1[(wm + i * 16 + r15) * BK + kg * 8];
        bl[i] = *(const bf16x8*)&lB1[(wn + i * 16 + r15) * BK + kg * 8];
      }
#pragma unroll
      for (int i = 0; i < 4; ++i)
#pragma unroll
        for (int j = 0; j < 4; ++j) {
          acc[i][j] = __builtin_amdgcn_mfma_f32_16x16x32_bf16(ah[i], bh[j], acc[i][j], 0, 0, 0);
          acc[i][j] = __builtin_amdgcn_mfma_f32_16x16x32_bf16(ah[i], bl[j], acc[i][j], 0, 0, 0);
          acc[i][j] = __builtin_amdgcn_mfma_f32_16x16x32_bf16(al[i], bh[j], acc[i][j], 0, 0, 0);
        }
    } else {
#pragma unroll
      for (int i = 0; i < 4; ++i)
#pragma unroll
        for (int j = 0; j < 4; ++j)
          acc[i][j] = __builtin_amdgcn_mfma_f32_16x16x32_bf16(ah[i], bh[j], acc[i][j], 0, 0, 0);
    }
  }

  // epilogue: C/D layout col=lane&15, row=(lane>>4)*4+r  [m89-verified]
#pragma unroll
  for (int i = 0; i < 4; ++i) {
    long rg = bm + wm + i * 16 + kg * 4;
#pragma unroll
    for (int j = 0; j < 4; ++j) {
      long cg = bn + wn + j * 16 + r15;
      f32x4 v = acc[i][j];
      if constexpr (MODE == 0) {
        float csq = aux0[cg];
#pragma unroll
        for (int r = 0; r < 4; ++r) C[(rg + r) * ldc + cg] = 2.f * v[r] - csq;
      } else if constexpr (MODE == 1) {
#pragma unroll
        for (int r = 0; r < 4; ++r) C[(rg + r) * ldc + cg] = v[r];
      } else {
        float bb = aux1[cg];
#pragma unroll
        for (int r = 0; r < 4; ++r)
          C[(rg + r) * ldc + cg] = v[r] + aux0[(rg + r) * ldc + cg] + bb;
      }
    }
  }
}

__global__ __launch_bounds__(256) void prep_split(const float* __restrict__ in,
                                                  u16* __restrict__ hi, u16* __restrict__ lo,
                                                  int n4) {
  int i = blockIdx.x * 256 + threadIdx.x;
  if (i >= n4) return;
  float4 v = ((const float4*)in)[i];
  ushort4 h, l;
  h.x = f2bf(v.x); l.x = f2bf(v.x - bf2f(h.x));
  h.y = f2bf(v.y); l.y = f2bf(v.y - bf2f(h.y));
  h.z = f2bf(v.z); l.z = f2bf(v.z - bf2f(h.z));
  h.w = f2bf(v.w); l.w = f2bf(v.w - bf2f(h.w));
  ((ushort4*)hi)[i] = h;
  ((ushort4*)lo)[i] = l;
}

__global__ __launch_bounds__(256) void prep_bf16(const float* __restrict__ in,
                                                 u16* __restrict__ o, int n4) {
  int i = blockIdx.x * 256 + threadIdx.x;
  if (i >= n4) return;
  float4 v = ((const float4*)in)[i];
  ushort4 h;
  h.x = f2bf(v.x); h.y = f2bf(v.y); h.z = f2bf(v.z); h.w = f2bf(v.w);
  ((ushort4*)o)[i] = h;
}

// one block per codebook row: split to hi/lo + row sum of squares
__global__ __launch_bounds__(256) void prep_cb(const float* __restrict__ cb,
                                               u16* __restrict__ hi, u16* __restrict__ lo,
                                               float* __restrict__ c_sq) {
  long k = blockIdx.x;
  int t = threadIdx.x, lane = t & 63, wave = t >> 6;
  float4 v = ((const float4*)(cb + k * 1024))[t];
  ushort4 h, l;
  h.x = f2bf(v.x); l.x = f2bf(v.x - bf2f(h.x));
  h.y = f2bf(v.y); l.y = f2bf(v.y - bf2f(h.y));
  h.z = f2bf(v.z); l.z = f2bf(v.z - bf2f(h.z));
  h.w = f2bf(v.w); l.w = f2bf(v.w - bf2f(h.w));
  ((ushort4*)(hi + k * 1024))[t] = h;
  ((ushort4*)(lo + k * 1024))[t] = l;
  float ss = v.x * v.x + v.y * v.y + v.z * v.z + v.w * v.w;
#pragma unroll
  for (int o = 32; o; o >>= 1) ss += __shfl_xor(ss, o);
  __shared__ float sc[4];
  if (lane == 0) sc[wave] = ss;
  __syncthreads();
  if (t == 0) c_sq[k] = sc[0] + sc[1] + sc[2] + sc[3];
}

// cbT[d][k] = bf16(cb[k][d]);  64x64 tiles
__global__ __launch_bounds__(256) void transpose_cb(const float* __restrict__ cb,
                                                    u16* __restrict__ cbT) {
  __shared__ u16 tt[64][65];
  long k0 = (long)blockIdx.x * 64, d0 = (long)blockIdx.y * 64;
  int t = threadIdx.x;
  int rr = t >> 4, cc = (t & 15) * 4;
#pragma unroll
  for (int p = 0; p < 4; ++p) {
    int r = rr + p * 16;
    float4 v = *(const float4*)(cb + (k0 + r) * 1024 + d0 + cc);
    tt[r][cc] = f2bf(v.x); tt[r][cc + 1] = f2bf(v.y);
    tt[r][cc + 2] = f2bf(v.z); tt[r][cc + 3] = f2bf(v.w);
  }
  __syncthreads();
#pragma unroll
  for (int p = 0; p < 4; ++p) {
    int d = rr + p * 16;
    ushort4 o;
    o.x = tt[cc][d]; o.y = tt[cc + 1][d]; o.z = tt[cc + 2][d]; o.w = tt[cc + 3][d];
    *(ushort4*)(cbT + (d0 + d) * 8192 + k0 + cc) = o;
  }
}

// one block per row of S [8192 floats]; writes q bf16 in-place over row start
__global__ __launch_bounds__(256) void softmax_rows(float* __restrict__ S) {
  long m = blockIdx.x;
  int t = threadIdx.x, lane = t & 63, wave = t >> 6;
  float* row = S + m * 8192;
  float4 v[8];
#pragma unroll
  for (int c = 0; c < 8; ++c) v[c] = ((const float4*)row)[c * 256 + t];
  float mx = -3.0e38f;
#pragma unroll
  for (int c = 0; c < 8; ++c)
    mx = fmaxf(mx, fmaxf(fmaxf(v[c].x, v[c].y), fmaxf(v[c].z, v[c].w)));
#pragma unroll
  for (int o = 32; o; o >>= 1) mx = fmaxf(mx, __shfl_xor(mx, o));
  __shared__ float sc[4];
  if (lane == 0) sc[wave] = mx;
  __syncthreads();
  mx = fmaxf(fmaxf(sc[0], sc[1]), fmaxf(sc[2], sc[3]));
  __syncthreads();
  float sum = 0.f;
#pragma unroll
  for (int c = 0; c < 8; ++c) {
    v[c].x = __expf(v[c].x - mx); v[c].y = __expf(v[c].y - mx);
    v[c].z = __expf(v[c].z - mx); v[c].w = __expf(v[c].w - mx);
    sum += v[c].x + v[c].y + v[c].z + v[c].w;
  }
#pragma unroll
  for (int o = 32; o; o >>= 1) sum += __shfl_xor(sum, o);
  if (lane == 0) sc[wave] = sum;
  __syncthreads();
  float rd = 1.f / (sc[0] + sc[1] + sc[2] + sc[3]);
  u16* q = (u16*)row;
#pragma unroll
  for (int c = 0; c < 8; ++c) {
    ushort4 o;
    o.x = f2bf(v[c].x * rd); o.y = f2bf(v[c].y * rd);
    o.z = f2bf(v[c].z * rd); o.w = f2bf(v[c].w * rd);
    ((ushort4*)q)[c * 256 + t] = o;
  }
}

// x = RMSNorm(h - z_e) * scale  -> bf16; one block per row
__global__ __launch_bounds__(256) void rms_x(const float* __restrict__ h,
                                             const float* __restrict__ z_e,
                                             const float* __restrict__ scale,
                                             u16* __restrict__ x) {
  long m = blockIdx.x;
  int t = threadIdx.x, lane = t & 63, wave = t >> 6;
  float4 hv = ((const float4*)(h + m * 1024))[t];
  float4 zv = ((const float4*)(z_e + m * 1024))[t];
  float4 r;
  r.x = hv.x - zv.x; r.y = hv.y - zv.y; r.z = hv.z - zv.z; r.w = hv.w - zv.w;
  float ss = r.x * r.x + r.y * r.y + r.z * r.z + r.w * r.w;
#pragma unroll
  for (int o = 32; o; o >>= 1) ss += __shfl_xor(ss, o);
  __shared__ float sc[4];
  if (lane == 0) sc[wave] = ss;
  __syncthreads();
  float tot = sc[0] + sc[1] + sc[2] + sc[3];
  float inv = 1.f / (sqrtf(tot * (1.f / 1024.f)) + 1e-8f);
  float4 s4 = ((const float4*)scale)[t];
  ushort4 o;
  o.x = f2bf(r.x * inv * s4.x); o.y = f2bf(r.y * inv * s4.y);
  o.z = f2bf(r.z * inv * s4.z); o.w = f2bf(r.w * inv * s4.w);
  ((ushort4*)(x + m * 1024))[t] = o;
}

extern "C" void kernel_launch(void* const* d_in, const int* in_sizes, int n_in,
                              void* d_out, int out_size, void* d_ws, size_t ws_size,
                              hipStream_t stream) {
  const float* h = (const float*)d_in[0];
  const float* cb = (const float*)d_in[1];
  const float* scale = (const float*)d_in[2];
  const float* W = (const float*)d_in[3];
  const float* b = (const float*)d_in[4];
  float* out = (float*)d_out;

  // ws layout: fixed buffers first (~136 MB), S_chunk takes the remainder.
  char* ws = (char*)d_ws;
  size_t off = 0;
  auto alloc = [&](size_t bytes) -> char* {
    char* p = ws + off;
    off = (off + bytes + 255) & ~(size_t)255;
    return p;
  };
  u16* h_hi  = (u16*)alloc(8192L * 1024 * 2);
  u16* h_lo  = (u16*)alloc(8192L * 1024 * 2);
  u16* cb_hi = (u16*)alloc(8192L * 1024 * 2);
  u16* cb_lo = (u16*)alloc(8192L * 1024 * 2);
  u16* cbT   = (u16*)alloc(1024L * 8192 * 2);
  u16* Wbf   = (u16*)alloc(1024L * 1024 * 2);
  float* c_sq = (float*)alloc(8192L * 4);
  float* z_e  = (float*)alloc(8192L * 1024 * 4);
  u16* x      = (u16*)alloc(8192L * 1024 * 2);
  float* S    = (float*)(ws + off);

  // rows per chunk, multiple of 128, from remaining workspace
  long RC = 128;
  if (ws_size > off) {
    long cap = (long)((ws_size - off) / (8192L * 4));
    cap = (cap / 128) * 128;
    if (cap > RC) RC = cap;
    if (RC > 8192) RC = 8192;
  }

  prep_split<<<8192, 256, 0, stream>>>(h, h_hi, h_lo, 2097152);
  prep_cb<<<8192, 256, 0, stream>>>(cb, cb_hi, cb_lo, c_sq);
  prep_bf16<<<1024, 256, 0, stream>>>(W, Wbf, 262144);
  transpose_cb<<<dim3(128, 16), 256, 0, stream>>>(cb, cbT);

  for (long r0 = 0; r0 < 8192; r0 += RC) {
    long rows = 8192 - r0;
    if (rows > RC) rows = RC;
    // S = 2*h@cb^T - c_sq   (split-3 bf16), rows [r0, r0+rows)
    gemm_bt<0><<<dim3(64, rows / 128), 256, 0, stream>>>(
        h_hi + r0 * 1024, h_lo + r0 * 1024, 1024L, cb_hi, cb_lo, 1024L,
        S, 8192L, 1024, c_sq, nullptr);
    // q = softmax(S) rows, bf16 in-place (row stride 16384 u16)
    softmax_rows<<<rows, 256, 0, stream>>>(S);
    // z_e[chunk] = q @ cb   (A = q bf16 lda 16384, B = cbT)
    gemm_bt<1><<<dim3(8, rows / 128), 256, 0, stream>>>(
        (u16*)S, nullptr, 16384L, cbT, nullptr, 8192L,
        z_e + r0 * 1024, 1024L, 8192, nullptr, nullptr);
  }

  // x = RMSNorm(h - z_e) * scale
  rms_x<<<8192, 256, 0, stream>>>(h, z_e, scale, x);
  // out = z_e + x @ W^T + b
  gemm_bt<2><<<dim3(8, 64), 256, 0, stream>>>(x, nullptr, 1024L, Wbf, nullptr, 1024L,
                                              out, 1024L, 1024, z_e, b);
}

// Round 3
// 984.284 us; speedup vs baseline: 1.2509x; 1.2509x over previous
//
#include <hip/hip_runtime.h>

typedef unsigned short u16;
typedef __attribute__((ext_vector_type(8))) short bf16x8;
typedef __attribute__((ext_vector_type(4))) float f32x4;

__device__ __forceinline__ u16 f2bf(float x) {
  unsigned int u = __float_as_uint(x);
  u = u + 0x7FFFu + ((u >> 16) & 1u);
  return (u16)(u >> 16);
}
__device__ __forceinline__ float bf2f(u16 v) {
  return __uint_as_float(((unsigned int)v) << 16);
}

typedef const __attribute__((address_space(1))) void gas_void;
typedef __attribute__((address_space(3))) void las_void;

__device__ __forceinline__ void gld_lds16(const u16* g, u16* l) {
  __builtin_amdgcn_global_load_lds((gas_void*)g, (las_void*)l, 16, 0, 0);
}

#define BM 128
#define BN 128
#define BK 32

// stage a [128][32] bf16 tile from row-major src (leading dim lda) into linear LDS
__device__ __forceinline__ void stage_tile(const u16* __restrict__ src, long lda,
                                           long row0, long k0, u16* ldst, int tid) {
  int wave = tid >> 6;
#pragma unroll
  for (int c = 0; c < 2; ++c) {
    int chunk = c * 256 + tid;      // 512 chunks x 8 elems = 128*32
    int r = chunk >> 2;
    int col = (chunk & 3) * 8;
    const u16* g = src + (row0 + r) * lda + k0 + col;
    u16* l = ldst + c * 2048 + wave * 512;  // HW adds lane*16B
    gld_lds16(g, l);
  }
}

// C[m][n] = sum_k A[m][k]*B[n][k]  (both row-major, K contiguous)
// MODE 0: split3 (A0+A1, B0+B1), epilogue C = 2*acc - aux0[n]          (logits, f32)
// MODE 2: plain, C = acc + aux0[m*ldc+n] + aux1[n]                     (z_q, f32)
// MODE 3: plain split-K over blockIdx.z (span KSPAN), bf16 partials    (z_e parts)
template <int MODE>
__global__ __launch_bounds__(256) void gemm_bt(
    const u16* __restrict__ A0, const u16* __restrict__ A1, long lda,
    const u16* __restrict__ B0, const u16* __restrict__ B1, long ldb,
    void* __restrict__ Cv, long ldc, int KSPAN,
    const float* __restrict__ aux0, const float* __restrict__ aux1, long zstride) {
  __shared__ __align__(16) u16 lA0[BM * BK];
  __shared__ __align__(16) u16 lB0[BN * BK];
  __shared__ __align__(16) u16 lA1[(MODE == 0) ? BM * BK : 8];
  __shared__ __align__(16) u16 lB1[(MODE == 0) ? BN * BK : 8];

  int tid = threadIdx.x;
  int wave = tid >> 6, lane = tid & 63;
  long bm = (long)blockIdx.y * BM, bn = (long)blockIdx.x * BN;
  int wm = (wave >> 1) * 64, wn = (wave & 1) * 64;
  int r15 = lane & 15, kg = lane >> 4;
  long kbase = 0;
  if constexpr (MODE == 3) kbase = (long)blockIdx.z * KSPAN;

  f32x4 acc[4][4];
#pragma unroll
  for (int i = 0; i < 4; ++i)
#pragma unroll
    for (int j = 0; j < 4; ++j) acc[i][j] = (f32x4){0.f, 0.f, 0.f, 0.f};

  for (int k0 = 0; k0 < KSPAN; k0 += BK) {
    __syncthreads();
    stage_tile(A0, lda, bm, kbase + k0, lA0, tid);
    stage_tile(B0, ldb, bn, kbase + k0, lB0, tid);
    if constexpr (MODE == 0) {
      stage_tile(A1, lda, bm, kbase + k0, lA1, tid);
      stage_tile(B1, ldb, bn, kbase + k0, lB1, tid);
    }
    __syncthreads();

    bf16x8 ah[4], bh[4];
#pragma unroll
    for (int i = 0; i < 4; ++i) {
      ah[i] = *(const bf16x8*)&lA0[(wm + i * 16 + r15) * BK + kg * 8];
      bh[i] = *(const bf16x8*)&lB0[(wn + i * 16 + r15) * BK + kg * 8];
    }
    if constexpr (MODE == 0) {
      bf16x8 al[4], bl[4];
#pragma unroll
      for (int i = 0; i < 4; ++i) {
        al[i] = *(const bf16x8*)&lA1[(wm + i * 16 + r15) * BK + kg * 8];
        bl[i] = *(const bf16x8*)&lB1[(wn + i * 16 + r15) * BK + kg * 8];
      }
#pragma unroll
      for (int i = 0; i < 4; ++i)
#pragma unroll
        for (int j = 0; j < 4; ++j) {
          acc[i][j] = __builtin_amdgcn_mfma_f32_16x16x32_bf16(ah[i], bh[j], acc[i][j], 0, 0, 0);
          acc[i][j] = __builtin_amdgcn_mfma_f32_16x16x32_bf16(ah[i], bl[j], acc[i][j], 0, 0, 0);
          acc[i][j] = __builtin_amdgcn_mfma_f32_16x16x32_bf16(al[i], bh[j], acc[i][j], 0, 0, 0);
        }
    } else {
#pragma unroll
      for (int i = 0; i < 4; ++i)
#pragma unroll
        for (int j = 0; j < 4; ++j)
          acc[i][j] = __builtin_amdgcn_mfma_f32_16x16x32_bf16(ah[i], bh[j], acc[i][j], 0, 0, 0);
    }
  }

  // epilogue: C/D layout col=lane&15, row=(lane>>4)*4+r  [m89-verified]
#pragma unroll
  for (int i = 0; i < 4; ++i) {
    long rg = bm + wm + i * 16 + kg * 4;
#pragma unroll
    for (int j = 0; j < 4; ++j) {
      long cg = bn + wn + j * 16 + r15;
      f32x4 v = acc[i][j];
      if constexpr (MODE == 0) {
        float* C = (float*)Cv;
        float csq = aux0[cg];
#pragma unroll
        for (int r = 0; r < 4; ++r) C[(rg + r) * ldc + cg] = 2.f * v[r] - csq;
      } else if constexpr (MODE == 2) {
        float* C = (float*)Cv;
        float bb = aux1[cg];
#pragma unroll
        for (int r = 0; r < 4; ++r)
          C[(rg + r) * ldc + cg] = v[r] + aux0[(rg + r) * ldc + cg] + bb;
      } else {
        u16* P = (u16*)Cv + (long)blockIdx.z * zstride;
#pragma unroll
        for (int r = 0; r < 4; ++r) P[(rg + r) * ldc + cg] = f2bf(v[r]);
      }
    }
  }
}

__global__ __launch_bounds__(256) void prep_split(const float* __restrict__ in,
                                                  u16* __restrict__ hi, u16* __restrict__ lo,
                                                  int n4) {
  int i = blockIdx.x * 256 + threadIdx.x;
  if (i >= n4) return;
  float4 v = ((const float4*)in)[i];
  ushort4 h, l;
  h.x = f2bf(v.x); l.x = f2bf(v.x - bf2f(h.x));
  h.y = f2bf(v.y); l.y = f2bf(v.y - bf2f(h.y));
  h.z = f2bf(v.z); l.z = f2bf(v.z - bf2f(h.z));
  h.w = f2bf(v.w); l.w = f2bf(v.w - bf2f(h.w));
  ((ushort4*)hi)[i] = h;
  ((ushort4*)lo)[i] = l;
}

__global__ __launch_bounds__(256) void prep_bf16(const float* __restrict__ in,
                                                 u16* __restrict__ o, int n4) {
  int i = blockIdx.x * 256 + threadIdx.x;
  if (i >= n4) return;
  float4 v = ((const float4*)in)[i];
  ushort4 h;
  h.x = f2bf(v.x); h.y = f2bf(v.y); h.z = f2bf(v.z); h.w = f2bf(v.w);
  ((ushort4*)o)[i] = h;
}

// one block per codebook row: split to hi/lo + row sum of squares
__global__ __launch_bounds__(256) void prep_cb(const float* __restrict__ cb,
                                               u16* __restrict__ hi, u16* __restrict__ lo,
                                               float* __restrict__ c_sq) {
  long k = blockIdx.x;
  int t = threadIdx.x, lane = t & 63, wave = t >> 6;
  float4 v = ((const float4*)(cb + k * 1024))[t];
  ushort4 h, l;
  h.x = f2bf(v.x); l.x = f2bf(v.x - bf2f(h.x));
  h.y = f2bf(v.y); l.y = f2bf(v.y - bf2f(h.y));
  h.z = f2bf(v.z); l.z = f2bf(v.z - bf2f(h.z));
  h.w = f2bf(v.w); l.w = f2bf(v.w - bf2f(h.w));
  ((ushort4*)(hi + k * 1024))[t] = h;
  ((ushort4*)(lo + k * 1024))[t] = l;
  float ss = v.x * v.x + v.y * v.y + v.z * v.z + v.w * v.w;
#pragma unroll
  for (int o = 32; o; o >>= 1) ss += __shfl_xor(ss, o);
  __shared__ float sc[4];
  if (lane == 0) sc[wave] = ss;
  __syncthreads();
  if (t == 0) c_sq[k] = sc[0] + sc[1] + sc[2] + sc[3];
}

// cbT[d][k] = bf16(cb[k][d]);  64x64 tiles
__global__ __launch_bounds__(256) void transpose_cb(const float* __restrict__ cb,
                                                    u16* __restrict__ cbT) {
  __shared__ u16 tt[64][65];
  long k0 = (long)blockIdx.x * 64, d0 = (long)blockIdx.y * 64;
  int t = threadIdx.x;
  int rr = t >> 4, cc = (t & 15) * 4;
#pragma unroll
  for (int p = 0; p < 4; ++p) {
    int r = rr + p * 16;
    float4 v = *(const float4*)(cb + (k0 + r) * 1024 + d0 + cc);
    tt[r][cc] = f2bf(v.x); tt[r][cc + 1] = f2bf(v.y);
    tt[r][cc + 2] = f2bf(v.z); tt[r][cc + 3] = f2bf(v.w);
  }
  __syncthreads();
#pragma unroll
  for (int p = 0; p < 4; ++p) {
    int d = rr + p * 16;
    ushort4 o;
    o.x = tt[cc][d]; o.y = tt[cc + 1][d]; o.z = tt[cc + 2][d]; o.w = tt[cc + 3][d];
    *(ushort4*)(cbT + (d0 + d) * 8192 + k0 + cc) = o;
  }
}

// one block per row of S [8192 floats]; writes q bf16 in-place over row start
__global__ __launch_bounds__(256) void softmax_rows(float* __restrict__ S) {
  long m = blockIdx.x;
  int t = threadIdx.x, lane = t & 63, wave = t >> 6;
  float* row = S + m * 8192;
  float4 v[8];
#pragma unroll
  for (int c = 0; c < 8; ++c) v[c] = ((const float4*)row)[c * 256 + t];
  float mx = -3.0e38f;
#pragma unroll
  for (int c = 0; c < 8; ++c)
    mx = fmaxf(mx, fmaxf(fmaxf(v[c].x, v[c].y), fmaxf(v[c].z, v[c].w)));
#pragma unroll
  for (int o = 32; o; o >>= 1) mx = fmaxf(mx, __shfl_xor(mx, o));
  __shared__ float sc[4];
  if (lane == 0) sc[wave] = mx;
  __syncthreads();
  mx = fmaxf(fmaxf(sc[0], sc[1]), fmaxf(sc[2], sc[3]));
  __syncthreads();
  float sum = 0.f;
#pragma unroll
  for (int c = 0; c < 8; ++c) {
    v[c].x = __expf(v[c].x - mx); v[c].y = __expf(v[c].y - mx);
    v[c].z = __expf(v[c].z - mx); v[c].w = __expf(v[c].w - mx);
    sum += v[c].x + v[c].y + v[c].z + v[c].w;
  }
#pragma unroll
  for (int o = 32; o; o >>= 1) sum += __shfl_xor(sum, o);
  if (lane == 0) sc[wave] = sum;
  __syncthreads();
  float rd = 1.f / (sc[0] + sc[1] + sc[2] + sc[3]);
  u16* q = (u16*)row;
#pragma unroll
  for (int c = 0; c < 8; ++c) {
    ushort4 o;
    o.x = f2bf(v[c].x * rd); o.y = f2bf(v[c].y * rd);
    o.z = f2bf(v[c].z * rd); o.w = f2bf(v[c].w * rd);
    ((ushort4*)q)[c * 256 + t] = o;
  }
}

// per chunk row: z_e = sum of 4 bf16 split-K partials (f32 out),
// then x = RMSNorm(h - z_e) * scale (bf16 out). h/z_e/x pre-offset to chunk.
__global__ __launch_bounds__(256) void reduce_rms(const u16* __restrict__ parts, long rows,
                                                  const float* __restrict__ h,
                                                  const float* __restrict__ scale,
                                                  float* __restrict__ z_e,
                                                  u16* __restrict__ x) {
  long m = blockIdx.x;
  int t = threadIdx.x, lane = t & 63, wave = t >> 6;
  long base = m * 1024 + t * 4;
  long sstride = rows * 1024;
  float4 ze = {0.f, 0.f, 0.f, 0.f};
#pragma unroll
  for (int s = 0; s < 4; ++s) {
    ushort4 p = *(const ushort4*)(parts + s * sstride + base);
    ze.x += bf2f(p.x); ze.y += bf2f(p.y); ze.z += bf2f(p.z); ze.w += bf2f(p.w);
  }
  *(float4*)(z_e + base) = ze;
  float4 hv = *(const float4*)(h + base);
  float4 r;
  r.x = hv.x - ze.x; r.y = hv.y - ze.y; r.z = hv.z - ze.z; r.w = hv.w - ze.w;
  float ss = r.x * r.x + r.y * r.y + r.z * r.z + r.w * r.w;
#pragma unroll
  for (int o = 32; o; o >>= 1) ss += __shfl_xor(ss, o);
  __shared__ float sc[4];
  if (lane == 0) sc[wave] = ss;
  __syncthreads();
  float tot = sc[0] + sc[1] + sc[2] + sc[3];
  float inv = 1.f / (sqrtf(tot * (1.f / 1024.f)) + 1e-8f);
  float4 s4 = *(const float4*)(scale + t * 4);
  ushort4 o;
  o.x = f2bf(r.x * inv * s4.x); o.y = f2bf(r.y * inv * s4.y);
  o.z = f2bf(r.z * inv * s4.z); o.w = f2bf(r.w * inv * s4.w);
  *(ushort4*)(x + base) = o;
}

extern "C" void kernel_launch(void* const* d_in, const int* in_sizes, int n_in,
                              void* d_out, int out_size, void* d_ws, size_t ws_size,
                              hipStream_t stream) {
  const float* h = (const float*)d_in[0];
  const float* cb = (const float*)d_in[1];
  const float* scale = (const float*)d_in[2];
  const float* W = (const float*)d_in[3];
  const float* b = (const float*)d_in[4];
  float* out = (float*)d_out;

  // ws layout: fixed buffers (~130 MB); tail = split-K partials (RC*8KB) + S chunk (RC*32KB)
  char* ws = (char*)d_ws;
  size_t off = 0;
  auto alloc = [&](size_t bytes) -> char* {
    char* p = ws + off;
    off = (off + bytes + 255) & ~(size_t)255;
    return p;
  };
  u16* h_hi  = (u16*)alloc(8192L * 1024 * 2);
  u16* h_lo  = (u16*)alloc(8192L * 1024 * 2);
  u16* cb_hi = (u16*)alloc(8192L * 1024 * 2);
  u16* cb_lo = (u16*)alloc(8192L * 1024 * 2);
  u16* cbT   = (u16*)alloc(1024L * 8192 * 2);
  u16* Wbf   = (u16*)alloc(1024L * 1024 * 2);
  float* c_sq = (float*)alloc(8192L * 4);
  float* z_e  = (float*)alloc(8192L * 1024 * 4);
  u16* x      = (u16*)alloc(8192L * 1024 * 2);

  // rows per chunk: each row needs 32768 B (S f32) + 8192 B (4 bf16 partials)
  long RC = 128;
  if (ws_size > off + 128 * 40960L) {
    long cap = (long)((ws_size - off) / 40960L);
    cap = (cap / 128) * 128;
    if (cap > RC) RC = cap;
    if (RC > 8192) RC = 8192;
  }
  u16* parts = (u16*)(ws + off);                       // [4][RC][1024] bf16
  float* S   = (float*)(ws + off + (size_t)RC * 8192); // [RC][8192] f32 (q bf16 in-place)

  prep_split<<<8192, 256, 0, stream>>>(h, h_hi, h_lo, 2097152);
  prep_cb<<<8192, 256, 0, stream>>>(cb, cb_hi, cb_lo, c_sq);
  prep_bf16<<<1024, 256, 0, stream>>>(W, Wbf, 262144);
  transpose_cb<<<dim3(128, 16), 256, 0, stream>>>(cb, cbT);

  for (long r0 = 0; r0 < 8192; r0 += RC) {
    long rows = 8192 - r0;
    if (rows > RC) rows = RC;
    // S = 2*h@cb^T - c_sq   (split-3 bf16), rows [r0, r0+rows)
    gemm_bt<0><<<dim3(64, rows / 128), 256, 0, stream>>>(
        h_hi + r0 * 1024, h_lo + r0 * 1024, 1024L, cb_hi, cb_lo, 1024L,
        S, 8192L, 1024, c_sq, nullptr, 0);
    // q = softmax(S) rows, bf16 in-place (row stride 16384 u16)
    softmax_rows<<<rows, 256, 0, stream>>>(S);
    // z_e partials: split-K=4 (span 2048), bf16 partial per z-slice
    gemm_bt<3><<<dim3(8, rows / 128, 4), 256, 0, stream>>>(
        (u16*)S, nullptr, 16384L, cbT, nullptr, 8192L,
        parts, 1024L, 2048, nullptr, nullptr, rows * 1024L);
    // z_e = sum(parts); x = RMSNorm(h - z_e)*scale
    reduce_rms<<<rows, 256, 0, stream>>>(parts, rows, h + r0 * 1024, scale,
                                         z_e + r0 * 1024, x + r0 * 1024);
  }

  // out = z_e + x @ W^T + b
  gemm_bt<2><<<dim3(8, 64), 256, 0, stream>>>(x, nullptr, 1024L, Wbf, nullptr, 1024L,
                                              out, 1024L, 1024, z_e, b, 0);
}